// Round 7
// baseline (129.792 us; speedup 1.0000x reference)
//
#include <hip/hip_runtime.h>
#include <math.h>

// Problem constants (fixed by the reference setup)
#define BATCH      16384
#define CLIP       50
#define DIM        64
#define PAD_IDX    100000
#define NITER      13   // ceil(CLIP/4): 4 friends per wave-iteration

// One wave per batch element.
// Lane mapping: sub = lane>>4 (friend slot within group of 4), li = lane&15
// (dim chunk: each lane owns dims [li*4, li*4+4) as a float4).
//
// R6: vmcnt-pipelined issue order. ie/w4 are loaded FIRST, then all 13 row
// gathers; v=ie*w then waits only for the two oldest loads (vmcnt(13)), and
// fe[i] consumption waits vmcnt(12-i) — tail gathers remain in flight under
// the shuffle/sigmoid chain instead of a full vmcnt(0) drain before compute.
// Friend ids live in SGPRs (uniform s_load), dying at gather issue, so the
// VGPR live set is ~fe[13]+misc ≈ 72 -> ~7 waves/SIMD naturally (no
// __launch_bounds__ min-waves coercion — that spilled in R3/R4).
__global__ __launch_bounds__(256) void gmf_kernel(
    const int*   __restrict__ user_indices,        // [B]
    const int*   __restrict__ item_indices,        // [B]
    const int*   __restrict__ user_friend_indices, // [NU, CLIP]
    const float* __restrict__ emb_user,            // [PAD_IDX+1, D] (pad row = 0)
    const float* __restrict__ emb_item,            // [NI, D]
    const float* __restrict__ affine_w,            // [D]
    const float* __restrict__ affine_b,            // [1]
    float*       __restrict__ out)                 // [B] ratings ++ [B*CLIP] gates
{
    const int wave = (blockIdx.x * blockDim.x + threadIdx.x) >> 6;
    const int lane = threadIdx.x & 63;
    if (wave >= BATCH) return;

    const int b   = wave;
    const int sub = lane >> 4;   // friend slot in group of 4
    const int li  = lane & 15;   // dim-chunk index

    const int u  = user_indices[b];   // wave-uniform
    const int it = item_indices[b];   // wave-uniform

    // ---- vmem #1,#2: ie and w4 (oldest in the queue) ----
    const float4 ie = *(const float4*)(emb_item + (size_t)it * DIM + li * 4);
    const float4 w4 = *(const float4*)(affine_w + li * 4);

    // ---- friend ids: wave-uniform scalar loads into SGPRs ----
    const int* fi_row = user_friend_indices + (size_t)u * CLIP;
    int4 idv[12];
    #pragma unroll
    for (int i = 0; i < 12; ++i)
        idv[i] = *(const int4*)(fi_row + 4 * i);         // uniform -> s_load
    const int2 idt = *(const int2*)(fi_row + 48);        // slots 48,49

    // ---- vmem #3..#15: all 13 row gathers, back-to-back ----
    // (pad row of emb_user is all-zero; ids die at issue; count folded in)
    float  cl = 0.f;     // per-lane real-friend count over its 13 slots
    float4 fe[NITER];
    #pragma unroll
    for (int i = 0; i < 12; ++i) {
        const int4 q = idv[i];
        const int  f = (sub == 0) ? q.x : (sub == 1) ? q.y : (sub == 2) ? q.z : q.w;
        cl += (f != PAD_IDX) ? 1.f : 0.f;
        fe[i] = *(const float4*)(emb_user + (size_t)f * DIM + li * 4);
    }
    {
        const int f = (sub == 0) ? idt.x : (sub == 1) ? idt.y : PAD_IDX;
        cl += (f != PAD_IDX) ? 1.f : 0.f;
        fe[12] = *(const float4*)(emb_user + (size_t)f * DIM + li * 4);
    }

    // v = ie*w: waits only for the two OLDEST vmem ops (13 gathers in flight).
    const float bias = affine_b[0];
    float4 v;
    v.x = ie.x * w4.x; v.y = ie.y * w4.y; v.z = ie.z * w4.z; v.w = ie.w * w4.w;

    float4 acc = make_float4(0.f, 0.f, 0.f, 0.f);
    float gkeep = 0.f;   // lane (li,sub) keeps gate of friend c = 4*li+sub

    #pragma unroll
    for (int i = 0; i < NITER; ++i) {
        // consuming fe[i] needs vmcnt(12-i): tail gathers stay in flight
        float p = fe[i].x * v.x + fe[i].y * v.y + fe[i].z * v.z + fe[i].w * v.w;
        p += __shfl_xor(p, 1, 64);
        p += __shfl_xor(p, 2, 64);
        p += __shfl_xor(p, 4, 64);
        p += __shfl_xor(p, 8, 64);

        const float g = 1.0f / (1.0f + __expf(-(p + bias)));

        acc.x += fe[i].x * g; acc.y += fe[i].y * g;
        acc.z += fe[i].z * g; acc.w += fe[i].w * g;

        if (li == i) gkeep = g;
    }

    // Friend count: lanes sharing `sub` are identical; sum the 4 sub-groups.
    float cntf = cl;
    cntf += __shfl_xor(cntf, 16, 64);
    cntf += __shfl_xor(cntf, 32, 64);

    // logits: full-wave reduce of acc·v (covers dim and friend-group sums).
    float q = acc.x * v.x + acc.y * v.y + acc.z * v.z + acc.w * v.w;
    q += __shfl_xor(q, 1, 64);
    q += __shfl_xor(q, 2, 64);
    q += __shfl_xor(q, 4, 64);
    q += __shfl_xor(q, 8, 64);
    q += __shfl_xor(q, 16, 64);
    q += __shfl_xor(q, 32, 64);

    const float rating = 1.0f / (1.0f + __expf(-(q / cntf + bias)));

    if (lane == 0)
        out[b] = rating;

    // Gate store: lane (li,sub) holds gate of friend c = 4*li+sub.
    const int c = 4 * li + sub;
    if (c < CLIP)
        out[BATCH + (size_t)b * CLIP + c] = gkeep;  // one 200B scattered store
}

extern "C" void kernel_launch(void* const* d_in, const int* in_sizes, int n_in,
                              void* d_out, int out_size, void* d_ws, size_t ws_size,
                              hipStream_t stream) {
    const int*   user_indices        = (const int*)  d_in[0];
    const int*   item_indices        = (const int*)  d_in[1];
    const int*   user_friend_indices = (const int*)  d_in[2];
    const float* emb_user            = (const float*)d_in[3];
    const float* emb_item            = (const float*)d_in[4];
    const float* affine_w            = (const float*)d_in[5];
    const float* affine_b            = (const float*)d_in[6];
    float*       out                 = (float*)d_out;

    const int threads = 256;
    const int blocks  = (BATCH * 64) / threads; // 4096
    gmf_kernel<<<blocks, threads, 0, stream>>>(
        user_indices, item_indices, user_friend_indices,
        emb_user, emb_item, affine_w, affine_b, out);
}